// Round 9
// baseline (225.864 us; speedup 1.0000x reference)
//
#include <hip/hip_runtime.h>
#include <hip/hip_bf16.h>
#include <hip/hip_fp16.h>
#include <stdint.h>

#define B_SIZE 8192
#define D_SIZE 2048
#define C_SIZE 128
#define N_INNER 255
#define N_LEAF 256

// fused gemm geometry: 256 blocks x 1024 thr (16 waves = 4 kg x 4 nw)
// wave tile: 32M x 64N x 512K ; per step: staged 128 k (4 kg x 32)
#define GBM 32
#define BKW 32                 // k per kg per step
#define NKG 4
#define KITER 16               // 512 / 32
#define LDA 136                // u16 row stride for staged A (272 B: 16B-aligned, 4-bank rotate)
#define NPADL 260              // f32 row stride for zbuf (1040 B: 16B-aligned, 4-bank rotate)

typedef _Float16 half8 __attribute__((ext_vector_type(8)));
typedef __fp16 pk16x2 __attribute__((ext_vector_type(2)));
typedef float f32x4 __attribute__((ext_vector_type(4)));
typedef unsigned short u16;

__device__ inline uint32_t pkh(float a, float b) {
    pk16x2 h = __builtin_amdgcn_cvt_pkrtz(a, b);
    return __builtin_bit_cast(uint32_t, h);
}
__device__ inline void split4(const float4 v, uint2& hi, uint2& lo) {
    pk16x2 a01 = __builtin_amdgcn_cvt_pkrtz(v.x, v.y);
    pk16x2 a23 = __builtin_amdgcn_cvt_pkrtz(v.z, v.w);
    float r0 = v.x - (float)a01[0];
    float r1 = v.y - (float)a01[1];
    float r2 = v.z - (float)a23[0];
    float r3 = v.w - (float)a23[1];
    hi = make_uint2(__builtin_bit_cast(uint32_t, a01), __builtin_bit_cast(uint32_t, a23));
    lo = make_uint2(pkh(r0, r1), pkh(r2, r3));
}

// ---------------- K-pre (merged): split W -> Wh/Wl f16 (rows>=255 zeroed) AND softmax -> Q, logQt ----------------
__global__ __launch_bounds__(256) void prep_kernel(
    const float* __restrict__ Wsrc, u16* __restrict__ Wh, u16* __restrict__ Wl,
    const float* __restrict__ lp, float* __restrict__ Q, float* __restrict__ logQt)
{
    int bid = blockIdx.x;
    int t = threadIdx.x;
    if (bid < 256) {
        int row = bid;
        int k = t * 8;
        uint2 h0, l0, h1, l1;
        if (row < N_INNER) {
            float4 v0 = *(const float4*)(Wsrc + (size_t)row * D_SIZE + k);
            float4 v1 = *(const float4*)(Wsrc + (size_t)row * D_SIZE + k + 4);
            split4(v0, h0, l0); split4(v1, h1, l1);
        } else {
            h0 = l0 = h1 = l1 = make_uint2(0u, 0u);
        }
        *(uint2*)&Wh[(size_t)row * D_SIZE + k]     = h0;
        *(uint2*)&Wh[(size_t)row * D_SIZE + k + 4] = h1;
        *(uint2*)&Wl[(size_t)row * D_SIZE + k]     = l0;
        *(uint2*)&Wl[(size_t)row * D_SIZE + k + 4] = l1;
    } else {
        int row = bid - 256;
        __shared__ float red[128];
        float v = 0.f;
        if (t < 128) { v = lp[row * C_SIZE + t]; red[t] = v; }
        __syncthreads();
        for (int s = 64; s > 0; s >>= 1) { if (t < s) red[t] = fmaxf(red[t], red[t + s]); __syncthreads(); }
        float mx = red[0]; __syncthreads();
        float e = 0.f;
        if (t < 128) { e = expf(v - mx); red[t] = e; }
        __syncthreads();
        for (int s = 64; s > 0; s >>= 1) { if (t < s) red[t] += red[t + s]; __syncthreads(); }
        float sum = red[0];
        if (t < 128) {
            Q[row * C_SIZE + t] = e / sum;
            logQt[(size_t)t * N_LEAF + row] = (v - mx) - logf(sum);
        }
    }
}

// ---------------- K1: FUSED gemm + sigmoid + tree path + penalties + loss + argmax ----------------
__global__ __launch_bounds__(1024, 4) void fused_kernel(
    const float* __restrict__ x, const u16* __restrict__ Wh, const u16* __restrict__ Wl,
    const float* __restrict__ bvec, const float* __restrict__ beta,
    const float* __restrict__ Q, const float* __restrict__ logQt,
    const int* __restrict__ target,
    float* __restrict__ g_num, float* __restrict__ g_den, float* __restrict__ g_loss,
    float* __restrict__ out)
{
    __shared__ __align__(16) u16 sAh[GBM * LDA];     // 8.7 KB
    __shared__ __align__(16) u16 sAl[GBM * LDA];     // 8.7 KB
    __shared__ __align__(16) float zbuf[GBM][NPADL]; // 33.3 KB
    __shared__ float s_num[128], s_den[128], s_loss;

    const int t = threadIdx.x;
    const int lane = t & 63, w = t >> 6;        // 16 waves
    const int kg = w >> 2, nw = w & 3;
    const int lr = lane & 15, lq = lane >> 4;
    const int m0 = blockIdx.x * GBM;

    // zero zbuf + accumulators (any later barrier orders these before use)
    for (int i = t; i < GBM * NPADL; i += 1024) ((float*)zbuf)[i] = 0.f;
    if (t < 128) s_num[t] = 0.f;
    else if (t < 256) s_den[t - 128] = 0.f;
    if (t == 0) s_loss = 0.f;

    f32x4 acc[2][4];
    #pragma unroll
    for (int mt = 0; mt < 2; ++mt)
        #pragma unroll
        for (int nt = 0; nt < 4; ++nt) acc[mt][nt] = (f32x4){0.f, 0.f, 0.f, 0.f};

    // cooperative A staging: thread -> (row, k-in-window); window = 4 kg x 32 k = 128
    const int srow = t >> 5;              // 0..31
    const int sk   = (t & 31) * 4;        // 0..124
    const int skg  = sk >> 5;             // kg window of this chunk
    const int sko  = sk & 31;
    const float* aptr = x + (size_t)(m0 + srow) * D_SIZE + skg * 512 + sko;

    float4 av = *(const float4*)aptr;     // prefetch step 0

    #pragma unroll 1
    for (int kt = 0; kt < KITER; ++kt) {
        __syncthreads();   // previous step's A reads complete
        {
            uint2 hi, lo; split4(av, hi, lo);
            *(uint2*)&sAh[srow * LDA + sk] = hi;
            *(uint2*)&sAl[srow * LDA + sk] = lo;
        }
        __syncthreads();   // staged A visible
        if (kt + 1 < KITER) av = *(const float4*)(aptr + (kt + 1) * BKW);  // prefetch next
        // B fragments: direct global->VGPR f16 (L2-resident pre-split W; full 64B lines)
        const int kbB = kg * 512 + kt * BKW;
        half8 bh[4], bl[4];
        #pragma unroll
        for (int nt = 0; nt < 4; ++nt) {
            int row = nw * 64 + nt * 16 + lr;
            bh[nt] = *(const half8*)(Wh + (size_t)row * D_SIZE + kbB + lq * 8);
            bl[nt] = *(const half8*)(Wl + (size_t)row * D_SIZE + kbB + lq * 8);
        }
        // A fragments from LDS (this wave's kg window)
        half8 ah[2], al[2];
        #pragma unroll
        for (int mt = 0; mt < 2; ++mt) {
            int off = (mt * 16 + lr) * LDA + kg * 32 + lq * 8;
            ah[mt] = *(const half8*)&sAh[off];
            al[mt] = *(const half8*)&sAl[off];
        }
        #pragma unroll
        for (int mt = 0; mt < 2; ++mt)
            #pragma unroll
            for (int nt = 0; nt < 4; ++nt) {
                acc[mt][nt] = __builtin_amdgcn_mfma_f32_16x16x32_f16(ah[mt], bh[nt], acc[mt][nt], 0, 0, 0);
                acc[mt][nt] = __builtin_amdgcn_mfma_f32_16x16x32_f16(ah[mt], bl[nt], acc[mt][nt], 0, 0, 0);
                acc[mt][nt] = __builtin_amdgcn_mfma_f32_16x16x32_f16(al[mt], bh[nt], acc[mt][nt], 0, 0, 0);
            }
    }

    // combine split-K via LDS float atomics (4-way per address)
    #pragma unroll
    for (int mt = 0; mt < 2; ++mt)
        #pragma unroll
        for (int nt = 0; nt < 4; ++nt)
            #pragma unroll
            for (int r = 0; r < 4; ++r)
                atomicAdd(&zbuf[mt * 16 + lq * 4 + r][nw * 64 + nt * 16 + lr], acc[mt][nt][r]);
    __syncthreads();

    // ---- path epilogue: wave w owns local rows 2w, 2w+1 ----
    const int c0 = lane * 4;
    float bet[4], bia[4];
    #pragma unroll
    for (int j = 0; j < 4; ++j) {
        int c = c0 + j;
        bet[j] = (c < N_INNER) ? beta[c] : 0.f;
        bia[j] = (c < N_INNER) ? bvec[c] : 0.f;
    }
    float pnum[4] = {0.f, 0.f, 0.f, 0.f};
    float pden[4] = {0.f, 0.f, 0.f, 0.f};
    float loss = 0.f;

    for (int i = 0; i < 2; ++i) {
        int rl = w * 2 + i;
        int r = m0 + rl;
        float4 zv4 = *(const float4*)&zbuf[rl][c0];
        float zv[4] = {zv4.x, zv4.y, zv4.z, zv4.w};
        float pv[4];
        #pragma unroll
        for (int j = 0; j < 4; ++j) {
            int c = c0 + j;
            pv[j] = (c < N_INNER) ? 1.f / (1.f + expf(-bet[j] * (zv[j] + bia[j]))) : 0.f;
        }
        *(float4*)&zbuf[rl][c0] = make_float4(pv[0], pv[1], pv[2], pv[3]);  // in-place p
        asm volatile("s_waitcnt lgkmcnt(0)" ::: "memory");  // own-wave row visibility

        int tg = target[r];
        float4 lq4 = *(const float4*)(logQt + (size_t)tg * N_LEAF + c0);
        float lqa[4] = {lq4.x, lq4.y, lq4.z, lq4.w};
        float lsum = 0.f, bestV = -1.f;
        int bestI = 0;
        #pragma unroll
        for (int j = 0; j < 4; ++j) {
            int leaf = c0 + j;
            float pl = 1.f;
            #pragma unroll
            for (int d = 0; d < 8; ++d) {
                int node = (1 << d) - 1 + (leaf >> (8 - d));
                int bit = (leaf >> (7 - d)) & 1;
                float pvn = zbuf[rl][node];
                pl *= bit ? pvn : (1.f - pvn);
            }
            lsum += pl * lqa[j];
            if (pl > bestV) { bestV = pl; bestI = leaf; }  // ascending j keeps lowest tie
        }
        if (lane < 32) {
            #pragma unroll
            for (int j = 0; j < 4; ++j) {
                int c = c0 + j;
                if (c < 127) {
                    int h = c + 1; int d = 31 - __clz(h);
                    float pp = 1.f;
                    for (int e = 0; e < d; ++e) {
                        int ha = h >> (d - e);
                        int bit = (h >> (d - 1 - e)) & 1;
                        float pvn = zbuf[rl][ha - 1];
                        pp *= bit ? pvn : (1.f - pvn);
                    }
                    pnum[j] += zbuf[rl][c] * pp;
                    pden[j] += pp;
                }
            }
        }
        #pragma unroll
        for (int m = 1; m < 64; m <<= 1) {
            lsum += __shfl_xor(lsum, m, 64);
            float ov = __shfl_xor(bestV, m, 64);
            int   oi = __shfl_xor(bestI, m, 64);
            if (ov > bestV || (ov == bestV && oi < bestI)) { bestV = ov; bestI = oi; }
        }
        loss += lsum;
        out[1 + (size_t)r * C_SIZE + lane]      = Q[bestI * C_SIZE + lane];
        out[1 + (size_t)r * C_SIZE + lane + 64] = Q[bestI * C_SIZE + lane + 64];
    }

    // block reduction (LDS atomics) then ONE global atomic per address per block
    if (lane < 32) {
        #pragma unroll
        for (int j = 0; j < 4; ++j) {
            int c = c0 + j;
            if (c < 127) {
                atomicAdd(&s_num[c], pnum[j]);
                atomicAdd(&s_den[c], pden[j]);
            }
        }
    }
    if (lane == 0) atomicAdd(&s_loss, loss);
    __syncthreads();
    if (t < 127)                    atomicAdd(&g_num[t], s_num[t]);
    else if (t >= 128 && t < 255)   atomicAdd(&g_den[t - 128], s_den[t - 128]);
    else if (t == 256)              atomicAdd(g_loss, s_loss);
}

// ---------------- K2: finalize total ----------------
__global__ __launch_bounds__(128) void finalize_kernel(
    const float* __restrict__ g_num, const float* __restrict__ g_den,
    const float* __restrict__ g_loss, float* __restrict__ out)
{
    __shared__ float red[128];
    int t = threadIdx.x;
    float term = 0.f;
    if (t < 127) {
        int d = 31 - __clz(t + 1);
        float lam = 0.1f * exp2f(-(float)(d + 1));
        float pen = g_num[t] / g_den[t];
        term = lam * 0.5f * (logf(pen) + logf(1.f - pen));
    }
    red[t] = term; __syncthreads();
    for (int s = 64; s > 0; s >>= 1) { if (t < s) red[t] += red[t + s]; __syncthreads(); }
    if (t == 0) out[0] = -(g_loss[0] / (float)B_SIZE) - red[0];
}

extern "C" void kernel_launch(void* const* d_in, const int* in_sizes, int n_in,
                              void* d_out, int out_size, void* d_ws, size_t ws_size,
                              hipStream_t stream)
{
    const float* x    = (const float*)d_in[0];
    const int*   tgt  = (const int*)d_in[1];
    const float* W    = (const float*)d_in[2];
    const float* b    = (const float*)d_in[3];
    const float* beta = (const float*)d_in[4];
    const float* lp   = (const float*)d_in[5];
    float* out = (float*)d_out;

    // ws (floats): [0:128) g_num, [128:256) g_den, [256] g_loss, pad 512,
    // Q (256x128), logQt (128x256), Wh/Wl (u16 256x2048 each)
    float* g_acc = (float*)d_ws;
    float* Q     = g_acc + 512;
    float* logQt = Q + (size_t)N_LEAF * C_SIZE;
    u16*   Wh    = (u16*)(logQt + (size_t)C_SIZE * N_LEAF);
    u16*   Wl    = Wh + (size_t)N_LEAF * D_SIZE;

    (void)hipMemsetAsync(d_ws, 0, 512 * sizeof(float), stream);

    prep_kernel<<<512, 256, 0, stream>>>(W, Wh, Wl, lp, Q, logQt);

    fused_kernel<<<B_SIZE / GBM, 1024, 0, stream>>>(
        x, Wh, Wl, b, beta, Q, logQt, tgt,
        g_acc, g_acc + 128, g_acc + 256, out);

    finalize_kernel<<<1, 128, 0, stream>>>(g_acc, g_acc + 128, g_acc + 256, out);
}